// Round 1
// baseline (6136.991 us; speedup 1.0000x reference)
//
#include <hip/hip_runtime.h>
#include <math.h>

constexpr int B = 4, C = 256, CC = 32, H = 64, W = 64, HW = H * W;
constexpr int G = 8, K = 9, GN = 32, CPG = C / GN;   // CPG = 8
constexpr int OFFC = 3 * G * K;                       // 216

// ---------------- resize (2x2 avg pool: rate=2, align_corners=False) ---------
__global__ void k_resize(const float* __restrict__ in, float* __restrict__ out) {
  int idx = blockIdx.x * 256 + threadIdx.x;
  if (idx >= B * CC * HW) return;
  int p = idx & (HW - 1);
  int c = (idx / HW) % CC;
  int b = idx / (HW * CC);
  int y = p >> 6, x = p & 63;
  const float* src = in + ((size_t)b * CC + c) * (2 * H) * (2 * W);
  const float* r0 = src + (2 * y) * (2 * W) + 2 * x;
  const float* r1 = r0 + 2 * W;
  out[idx] = 0.25f * (r0[0] + r0[1] + r1[0] + r1[1]);
}

// ---------------- 1x1 conv over (optional) two concatenated inputs -----------
__global__ void k_conv1x1(const float* __restrict__ in1, int c1,
                          const float* __restrict__ in2, int c2,
                          const float* __restrict__ w, const float* __restrict__ bias,
                          float* __restrict__ out) {
  int p = blockIdx.x * 256 + threadIdx.x;   // pixel
  int o = blockIdx.y;                       // out channel
  int b = blockIdx.z;
  int cout = gridDim.y;
  int cin = c1 + c2;
  const float* wr = w + (size_t)o * cin;
  float acc = bias[o];
  const float* i1 = in1 + (size_t)b * c1 * HW + p;
  for (int ci = 0; ci < c1; ++ci) acc += wr[ci] * i1[(size_t)ci * HW];
  const float* i2 = in2 + (size_t)b * c2 * HW + p;
  for (int ci = 0; ci < c2; ++ci) acc += wr[c1 + ci] * i2[(size_t)ci * HW];
  out[((size_t)b * cout + o) * HW + p] = acc;
}

// ---------------- GroupNorm (32 groups) + SiLU, block per (group,b) ----------
__global__ void k_gn_silu(const float* __restrict__ in, float* __restrict__ out,
                          const float* __restrict__ gamma, const float* __restrict__ beta) {
  int g = blockIdx.x, b = blockIdx.y;
  const float* base = in + ((size_t)b * C + g * CPG) * HW;
  float s = 0.f, s2 = 0.f;
  for (int i = threadIdx.x; i < CPG * HW; i += 256) {
    float v = base[i]; s += v; s2 += v * v;
  }
  #pragma unroll
  for (int off = 32; off > 0; off >>= 1) {
    s  += __shfl_down(s, off);
    s2 += __shfl_down(s2, off);
  }
  __shared__ float sh[8];
  __shared__ float mi[2];
  int wid = threadIdx.x >> 6, lane = threadIdx.x & 63;
  if (lane == 0) { sh[wid] = s; sh[4 + wid] = s2; }
  __syncthreads();
  if (threadIdx.x == 0) {
    float ts = sh[0] + sh[1] + sh[2] + sh[3];
    float t2 = sh[4] + sh[5] + sh[6] + sh[7];
    float mean = ts * (1.f / (CPG * HW));
    float var  = t2 * (1.f / (CPG * HW)) - mean * mean;
    mi[0] = mean; mi[1] = rsqrtf(var + 1e-6f);
  }
  __syncthreads();
  float mean = mi[0], inv = mi[1];
  float* ob = out + ((size_t)b * C + g * CPG) * HW;
  for (int i = threadIdx.x; i < CPG * HW; i += 256) {
    int c = g * CPG + (i >> 12);            // i / HW
    float v = (base[i] - mean) * inv * gamma[c] + beta[c];
    ob[i] = v / (1.f + expf(-v));           // SiLU
  }
}

// ---------------- depthwise 7x7, pad 3 ---------------------------------------
__global__ void k_dw7(const float* __restrict__ in, const float* __restrict__ w,
                      const float* __restrict__ bias, float* __restrict__ out) {
  int p = blockIdx.x * 256 + threadIdx.x;
  int c = blockIdx.y, b = blockIdx.z;
  int y = p >> 6, x = p & 63;
  const float* src = in + ((size_t)b * C + c) * HW;
  const float* wk = w + c * 49;
  float acc = bias[c];
  for (int ky = 0; ky < 7; ++ky) {
    int yy = y + ky - 3;
    if ((unsigned)yy >= (unsigned)H) continue;
    const float* row = src + yy * W;
    #pragma unroll
    for (int kx = 0; kx < 7; ++kx) {
      int xx = x + kx - 3;
      if ((unsigned)xx >= (unsigned)W) continue;
      acc += wk[ky * 7 + kx] * row[xx];
    }
  }
  out[((size_t)b * C + c) * HW + p] = acc;
}

// ---------------- 3x3 conv, pad 1, Cin=256 -----------------------------------
__global__ void k_conv3x3(const float* __restrict__ in, const float* __restrict__ w,
                          const float* __restrict__ bias, float* __restrict__ out) {
  int p = blockIdx.x * 256 + threadIdx.x;
  int o = blockIdx.y, b = blockIdx.z;
  int cout = gridDim.y;
  int y = p >> 6, x = p & 63;
  const float* src = in + (size_t)b * C * HW;
  const float* wr = w + (size_t)o * C * 9;
  float acc = bias[o];
  bool y0ok = (y > 0), y2ok = (y < H - 1);
  bool x0ok = (x > 0), x2ok = (x < W - 1);
  for (int ci = 0; ci < C; ++ci) {
    const float* sc = src + (size_t)ci * HW + y * W + x;
    const float* wc = wr + ci * 9;
    float a = 0.f;
    if (y0ok) {
      if (x0ok) a += wc[0] * sc[-W - 1];
      a += wc[1] * sc[-W];
      if (x2ok) a += wc[2] * sc[-W + 1];
    }
    if (x0ok) a += wc[3] * sc[-1];
    a += wc[4] * sc[0];
    if (x2ok) a += wc[5] * sc[1];
    if (y2ok) {
      if (x0ok) a += wc[6] * sc[W - 1];
      a += wc[7] * sc[W];
      if (x2ok) a += wc[8] * sc[W + 1];
    }
    acc += a;
  }
  out[((size_t)b * cout + o) * HW + p] = acc;
}

// ---------------- modulated deformable conv 3x3, G=8 -------------------------
// co channels: [0,144) = offsets ((g*K+k)*2 = dy, +1 = dx), [144,216) = mask logits.
__global__ __launch_bounds__(256) void k_deform(
    const float* __restrict__ xm, const float* __restrict__ co,
    const float* __restrict__ w, const float* __restrict__ bias,
    float* __restrict__ out) {
  constexpr int DP = 8;                 // pixels per block
  __shared__ float s[DP][K][C];         // 72 KB modulated samples
  __shared__ float ody[DP][K][G], odx[DP][K][G], om[DP][K][G];
  int b = blockIdx.y;
  int p0 = blockIdx.x * DP;
  const float* cob = co + (size_t)b * OFFC * HW;

  // phase 0: offsets + masks for this pixel tile
  for (int i = threadIdx.x; i < DP * K * G; i += 256) {
    int g = i % G, k = (i / G) % K, pi = i / (G * K);
    int p = p0 + pi;
    int cb = (g * K + k) * 2;
    ody[pi][k][g] = cob[(size_t)cb * HW + p];
    odx[pi][k][g] = cob[(size_t)(cb + 1) * HW + p];
    float ml = cob[(size_t)(144 + g * K + k) * HW + p];
    om[pi][k][g] = 1.f / (1.f + expf(-ml));
  }
  __syncthreads();

  // phase 1: modulated bilinear samples -> LDS
  for (int i = threadIdx.x; i < DP * K * C; i += 256) {
    int ci = i & (C - 1);
    int k = (i >> 8) % K;
    int pi = i / (C * K);
    int g = ci >> 5;
    int p = p0 + pi;
    int py = p >> 6, px = p & 63;
    int kh = k / 3 - 1, kw = k % 3 - 1;
    float yy = (float)(py + kh) + ody[pi][k][g];
    float xx = (float)(px + kw) + odx[pi][k][g];
    float y0f = floorf(yy), x0f = floorf(xx);
    float wy = yy - y0f, wx = xx - x0f;
    int y0 = (int)y0f, x0 = (int)x0f;
    const float* img = xm + ((size_t)b * C + ci) * HW;
    bool yv0 = (unsigned)y0 < (unsigned)H, yv1 = (unsigned)(y0 + 1) < (unsigned)H;
    bool xv0 = (unsigned)x0 < (unsigned)W, xv1 = (unsigned)(x0 + 1) < (unsigned)W;
    float v00 = (yv0 && xv0) ? img[y0 * W + x0] : 0.f;
    float v01 = (yv0 && xv1) ? img[y0 * W + x0 + 1] : 0.f;
    float v10 = (yv1 && xv0) ? img[(y0 + 1) * W + x0] : 0.f;
    float v11 = (yv1 && xv1) ? img[(y0 + 1) * W + x0 + 1] : 0.f;
    float v = (1.f - wy) * ((1.f - wx) * v00 + wx * v01)
            + wy * ((1.f - wx) * v10 + wx * v11);
    s[pi][k][ci] = v * om[pi][k][g];
  }
  __syncthreads();

  // phase 2: contraction — thread owns 2 output channels x 4 pixels
  int t = threadIdx.x;
  int oi = (t & 127) * 2;
  int ph = (t >> 7) * 4;
  float acc0[4], acc1[4];
  #pragma unroll
  for (int q = 0; q < 4; ++q) { acc0[q] = bias[oi]; acc1[q] = bias[oi + 1]; }
  const float* w0 = w + (size_t)oi * C * 9;
  const float* w1 = w0 + C * 9;
  for (int ci = 0; ci < C; ci += 4) {
    float wr0[36], wr1[36];
    const float4* pw0 = (const float4*)(w0 + ci * 9);
    const float4* pw1 = (const float4*)(w1 + ci * 9);
    #pragma unroll
    for (int j = 0; j < 9; ++j) {
      float4 a = pw0[j]; float4 bq = pw1[j];
      wr0[4 * j] = a.x;  wr0[4 * j + 1] = a.y;  wr0[4 * j + 2] = a.z;  wr0[4 * j + 3] = a.w;
      wr1[4 * j] = bq.x; wr1[4 * j + 1] = bq.y; wr1[4 * j + 2] = bq.z; wr1[4 * j + 3] = bq.w;
    }
    #pragma unroll
    for (int k = 0; k < K; ++k) {
      #pragma unroll
      for (int q = 0; q < 4; ++q) {
        const float4 sv = *(const float4*)&s[ph + q][k][ci];
        acc0[q] += wr0[k] * sv.x + wr0[9 + k] * sv.y + wr0[18 + k] * sv.z + wr0[27 + k] * sv.w;
        acc1[q] += wr1[k] * sv.x + wr1[9 + k] * sv.y + wr1[18 + k] * sv.z + wr1[27 + k] * sv.w;
      }
    }
  }
  #pragma unroll
  for (int q = 0; q < 4; ++q) {
    out[((size_t)b * C + oi) * HW + p0 + ph + q]     = acc0[q];
    out[((size_t)b * C + oi + 1) * HW + p0 + ph + q] = acc1[q];
  }
}

extern "C" void kernel_launch(void* const* d_in, const int* in_sizes, int n_in,
                              void* d_out, int out_size, void* d_ws, size_t ws_size,
                              hipStream_t stream) {
  const float* x_main  = (const float*)d_in[0];
  const float* inpfeat = (const float*)d_in[1];
  const float* w1a = (const float*)d_in[2];
  const float* b1a = (const float*)d_in[3];
  const float* g1  = (const float*)d_in[4];
  const float* be1 = (const float*)d_in[5];
  const float* w1b = (const float*)d_in[6];
  const float* b1b = (const float*)d_in[7];
  const float* g2  = (const float*)d_in[8];
  const float* be2 = (const float*)d_in[9];
  const float* w1c = (const float*)d_in[10];
  const float* b1c = (const float*)d_in[11];
  const float* w2  = (const float*)d_in[12];
  const float* b2  = (const float*)d_in[13];
  const float* g3  = (const float*)d_in[14];
  const float* be3 = (const float*)d_in[15];
  const float* w_off = (const float*)d_in[16];
  const float* b_off = (const float*)d_in[17];
  const float* w_dcn = (const float*)d_in[18];
  const float* b_dcn = (const float*)d_in[19];

  float* warp_out = (float*)d_out;                      // output 0 [B,C,H,W]
  float* off_out  = warp_out + (size_t)B * C * HW;      // output 1 [B,C,H,W]

  // workspace: r_inp (2MB) + fA (16MB). warp_out half of d_out doubles as fB.
  float* r_inp = (float*)d_ws;                          // B*CC*HW
  float* fA = r_inp + (size_t)B * CC * HW;              // B*C*HW
  float* fB = warp_out;                                 // B*C*HW scratch until last kernel
  float* co = fA;                                       // reuse fA once dead (needs 13.5MB<16MB)

  k_resize <<<dim3((B * CC * HW) / 256), 256, 0, stream>>>(inpfeat, r_inp);
  k_conv1x1<<<dim3(HW / 256, C, B), 256, 0, stream>>>(r_inp, CC, x_main, C, w1a, b1a, fA);
  k_gn_silu<<<dim3(GN, B), 256, 0, stream>>>(fA, fA, g1, be1);
  k_dw7    <<<dim3(HW / 256, C, B), 256, 0, stream>>>(fA, w1b, b1b, fB);
  k_gn_silu<<<dim3(GN, B), 256, 0, stream>>>(fB, fB, g2, be2);
  k_conv1x1<<<dim3(HW / 256, C, B), 256, 0, stream>>>(fB, C, fB, 0, w1c, b1c, fA);
  k_conv3x3<<<dim3(HW / 256, C, B), 256, 0, stream>>>(fA, w2, b2, fB);
  k_gn_silu<<<dim3(GN, B), 256, 0, stream>>>(fB, off_out, g3, be3);
  k_conv3x3<<<dim3(HW / 256, OFFC, B), 256, 0, stream>>>(off_out, w_off, b_off, co);
  k_deform <<<dim3(HW / 8, B), 256, 0, stream>>>(x_main, co, w_dcn, b_dcn, warp_out);
}

// Round 2
// 1818.199 us; speedup vs baseline: 3.3753x; 3.3753x over previous
//
#include <hip/hip_runtime.h>
#include <math.h>

constexpr int B = 4, C = 256, CC = 32, H = 64, W = 64, HW = H * W;
constexpr int G = 8, K = 9, GN = 32, CPG = C / GN;   // CPG = 8
constexpr int OFFC = 3 * G * K;                       // 216

typedef __attribute__((ext_vector_type(8))) short short8;
typedef __attribute__((ext_vector_type(4))) float f32x4;

__device__ inline short f2bf(float f) {
  unsigned u = __builtin_bit_cast(unsigned, f);
  return (short)((u + 0x7FFFu + ((u >> 16) & 1u)) >> 16);
}

// ---------------- resize (2x2 avg pool: rate=2, align_corners=False) ---------
__global__ void k_resize(const float* __restrict__ in, float* __restrict__ out) {
  int idx = blockIdx.x * 256 + threadIdx.x;
  if (idx >= B * CC * HW) return;
  int p = idx & (HW - 1);
  int c = (idx / HW) % CC;
  int b = idx / (HW * CC);
  int y = p >> 6, x = p & 63;
  const float* src = in + ((size_t)b * CC + c) * (2 * H) * (2 * W);
  const float* r0 = src + (2 * y) * (2 * W) + 2 * x;
  const float* r1 = r0 + 2 * W;
  out[idx] = 0.25f * (r0[0] + r0[1] + r1[0] + r1[1]);
}

// ---------------- transpose+convert: fp32 [Csrc][HW] -> bf16 [HW][Cdst] ------
__global__ void k_transpose(const float* __restrict__ src, short* __restrict__ dst,
                            int Csrc, int Cdst, int coff) {
  int t = threadIdx.x;
  int p0 = blockIdx.x * 64;
  int cc0 = blockIdx.y * 32;
  int b = blockIdx.z;
  int px = t >> 2, cq = t & 3;
  const float* s = src + ((size_t)b * Csrc + cc0 + cq * 8) * HW + p0 + px;
  short8 v;
  #pragma unroll
  for (int j = 0; j < 8; ++j) v[j] = f2bf(s[(size_t)j * HW]);
  *(short8*)(dst + ((size_t)b * HW + p0 + px) * Cdst + coff + cc0 + cq * 8) = v;
}

// ---------------- weight transform: [Cout][Cin][T] fp32 -> [T][Cout][Cin] bf16
template<int TAPS>
__global__ void k_wt(const float* __restrict__ w, short* __restrict__ wT,
                     int Cout, int Cin) {
  int id = blockIdx.x * 256 + threadIdx.x;
  if (id >= Cout * Cin) return;
  if (TAPS == 1) {
    wT[id] = f2bf(w[id]);
  } else {
    int o = id / Cin, ci = id % Cin;
    #pragma unroll
    for (int k = 0; k < 9; ++k)
      wT[((size_t)k * Cout + o) * Cin + ci] = f2bf(w[(size_t)id * 9 + k]);
  }
}

// ---------------- MFMA implicit-GEMM conv (taps=1 or 9, pad=(taps==9)) -------
// gT: [B][HW][CIN] bf16, wT: [TAPS][COUT][CIN] bf16, out: [B][COUT][HW] fp32
template<int CIN, int COUT, int TAPS>
__global__ __launch_bounds__(256) void k_mfma_conv(
    const short* __restrict__ gT, const short* __restrict__ wT,
    const float* __restrict__ bias, float* __restrict__ out) {
  constexpr int POS = (TAPS == 9) ? 4 * 66 : 128;   // staged positions
  constexpr int PSTR = 40;                          // u16 per position (80 B)
  __shared__ short lds[POS * PSTR];
  const int tid = threadIdx.x;
  const int lane = tid & 63, wv = tid >> 6;
  const int l15 = lane & 15, l4 = lane >> 4;
  const int b = blockIdx.z;
  const int o0 = blockIdx.y * 64;
  const int p0 = blockIdx.x * 128;
  const int y0 = p0 >> 6;                           // 2 image rows per block

  f32x4 acc[4][2];
  #pragma unroll
  for (int mt = 0; mt < 4; ++mt)
    #pragma unroll
    for (int nt = 0; nt < 2; ++nt) acc[mt][nt] = (f32x4)0.f;

  const short* gTb = gT + (size_t)b * HW * CIN;

  for (int ck = 0; ck < CIN / 32; ++ck) {
    const int ci0 = ck * 32;
    __syncthreads();
    // stage B-tile (with zero halo for 3x3) into LDS
    for (int i = tid; i < POS * 4; i += 256) {
      int pos = i >> 2, cq = i & 3;
      short8 v = {0, 0, 0, 0, 0, 0, 0, 0};
      if (TAPS == 9) {
        int r = pos / 66;
        int cx = pos - r * 66 - 1;
        int y = y0 - 1 + r;
        if ((unsigned)y < (unsigned)H && (unsigned)cx < (unsigned)W)
          v = *(const short8*)(gTb + (size_t)(y * W + cx) * CIN + ci0 + cq * 8);
      } else {
        v = *(const short8*)(gTb + (size_t)(p0 + pos) * CIN + ci0 + cq * 8);
      }
      *(short8*)(lds + pos * PSTR + cq * 8) = v;
    }
    __syncthreads();

    for (int tap = 0; tap < TAPS; ++tap) {
      // A fragments: lane holds W[o0+mt*16+l15][ci0 + l4*8 + j]
      short8 a[4];
      #pragma unroll
      for (int mt = 0; mt < 4; ++mt) {
        int o_r = o0 + mt * 16 + l15;
        if (COUT % 64 == 0 || o_r < COUT)
          a[mt] = *(const short8*)(wT + ((size_t)tap * COUT + o_r) * CIN + ci0 + l4 * 8);
        else
          a[mt] = (short8){0, 0, 0, 0, 0, 0, 0, 0};
      }
      // B fragments from LDS (shifted window for 3x3)
      short8 bb[2];
      #pragma unroll
      for (int nt = 0; nt < 2; ++nt) {
        int pos;
        if (TAPS == 9) {
          int dy = tap / 3 - 1, dx = tap % 3 - 1;
          int row = (wv >> 1) + dy + 1;
          int col = (wv & 1) * 32 + nt * 16 + l15 + dx + 1;
          pos = row * 66 + col;
        } else {
          pos = wv * 32 + nt * 16 + l15;
        }
        bb[nt] = *(const short8*)(lds + pos * PSTR + l4 * 8);
      }
      #pragma unroll
      for (int mt = 0; mt < 4; ++mt)
        #pragma unroll
        for (int nt = 0; nt < 2; ++nt)
          acc[mt][nt] = __builtin_amdgcn_mfma_f32_16x16x32_bf16(
              a[mt], bb[nt], acc[mt][nt], 0, 0, 0);
    }
  }

  // epilogue: D row = o0 + mt*16 + l4*4 + r, col(pixel) = p0 + wv*32 + nt*16 + l15
  #pragma unroll
  for (int mt = 0; mt < 4; ++mt) {
    #pragma unroll
    for (int nt = 0; nt < 2; ++nt) {
      int p = p0 + wv * 32 + nt * 16 + l15;
      #pragma unroll
      for (int r = 0; r < 4; ++r) {
        int oo = o0 + mt * 16 + l4 * 4 + r;
        if (COUT % 64 == 0 || oo < COUT)
          out[((size_t)b * COUT + oo) * HW + p] = acc[mt][nt][r] + bias[oo];
      }
    }
  }
}

// ---------------- GroupNorm (32 groups) + SiLU, block per (group,b) ----------
__global__ void k_gn_silu(const float* __restrict__ in, float* __restrict__ out,
                          const float* __restrict__ gamma, const float* __restrict__ beta) {
  int g = blockIdx.x, b = blockIdx.y;
  const float* base = in + ((size_t)b * C + g * CPG) * HW;
  float s = 0.f, s2 = 0.f;
  for (int i = threadIdx.x; i < CPG * HW; i += 256) {
    float v = base[i]; s += v; s2 += v * v;
  }
  #pragma unroll
  for (int off = 32; off > 0; off >>= 1) {
    s  += __shfl_down(s, off);
    s2 += __shfl_down(s2, off);
  }
  __shared__ float sh[8];
  __shared__ float mi[2];
  int wid = threadIdx.x >> 6, lane = threadIdx.x & 63;
  if (lane == 0) { sh[wid] = s; sh[4 + wid] = s2; }
  __syncthreads();
  if (threadIdx.x == 0) {
    float ts = sh[0] + sh[1] + sh[2] + sh[3];
    float t2 = sh[4] + sh[5] + sh[6] + sh[7];
    float mean = ts * (1.f / (CPG * HW));
    float var  = t2 * (1.f / (CPG * HW)) - mean * mean;
    mi[0] = mean; mi[1] = rsqrtf(var + 1e-6f);
  }
  __syncthreads();
  float mean = mi[0], inv = mi[1];
  float* ob = out + ((size_t)b * C + g * CPG) * HW;
  for (int i = threadIdx.x; i < CPG * HW; i += 256) {
    int c = g * CPG + (i >> 12);
    float v = (base[i] - mean) * inv * gamma[c] + beta[c];
    ob[i] = v / (1.f + expf(-v));
  }
}

// ---------------- depthwise 7x7, pad 3 ---------------------------------------
__global__ void k_dw7(const float* __restrict__ in, const float* __restrict__ w,
                      const float* __restrict__ bias, float* __restrict__ out) {
  int p = blockIdx.x * 256 + threadIdx.x;
  int c = blockIdx.y, b = blockIdx.z;
  int y = p >> 6, x = p & 63;
  const float* src = in + ((size_t)b * C + c) * HW;
  const float* wk = w + c * 49;
  float acc = bias[c];
  for (int ky = 0; ky < 7; ++ky) {
    int yy = y + ky - 3;
    if ((unsigned)yy >= (unsigned)H) continue;
    const float* row = src + yy * W;
    #pragma unroll
    for (int kx = 0; kx < 7; ++kx) {
      int xx = x + kx - 3;
      if ((unsigned)xx >= (unsigned)W) continue;
      acc += wk[ky * 7 + kx] * row[xx];
    }
  }
  out[((size_t)b * C + c) * HW + p] = acc;
}

// ---------------- modulated deformable conv 3x3, G=8 -------------------------
__global__ __launch_bounds__(256) void k_deform(
    const float* __restrict__ xm, const float* __restrict__ co,
    const float* __restrict__ w, const float* __restrict__ bias,
    float* __restrict__ out) {
  constexpr int DP = 8;
  __shared__ float s[DP][K][C];
  __shared__ float ody[DP][K][G], odx[DP][K][G], om[DP][K][G];
  int b = blockIdx.y;
  int p0 = blockIdx.x * DP;
  const float* cob = co + (size_t)b * OFFC * HW;

  for (int i = threadIdx.x; i < DP * K * G; i += 256) {
    int g = i % G, k = (i / G) % K, pi = i / (G * K);
    int p = p0 + pi;
    int cb = (g * K + k) * 2;
    ody[pi][k][g] = cob[(size_t)cb * HW + p];
    odx[pi][k][g] = cob[(size_t)(cb + 1) * HW + p];
    float ml = cob[(size_t)(144 + g * K + k) * HW + p];
    om[pi][k][g] = 1.f / (1.f + expf(-ml));
  }
  __syncthreads();

  for (int i = threadIdx.x; i < DP * K * C; i += 256) {
    int ci = i & (C - 1);
    int k = (i >> 8) % K;
    int pi = i / (C * K);
    int g = ci >> 5;
    int p = p0 + pi;
    int py = p >> 6, px = p & 63;
    int kh = k / 3 - 1, kw = k % 3 - 1;
    float yy = (float)(py + kh) + ody[pi][k][g];
    float xx = (float)(px + kw) + odx[pi][k][g];
    float y0f = floorf(yy), x0f = floorf(xx);
    float wy = yy - y0f, wx = xx - x0f;
    int y0 = (int)y0f, x0 = (int)x0f;
    const float* img = xm + ((size_t)b * C + ci) * HW;
    bool yv0 = (unsigned)y0 < (unsigned)H, yv1 = (unsigned)(y0 + 1) < (unsigned)H;
    bool xv0 = (unsigned)x0 < (unsigned)W, xv1 = (unsigned)(x0 + 1) < (unsigned)W;
    float v00 = (yv0 && xv0) ? img[y0 * W + x0] : 0.f;
    float v01 = (yv0 && xv1) ? img[y0 * W + x0 + 1] : 0.f;
    float v10 = (yv1 && xv0) ? img[(y0 + 1) * W + x0] : 0.f;
    float v11 = (yv1 && xv1) ? img[(y0 + 1) * W + x0 + 1] : 0.f;
    float v = (1.f - wy) * ((1.f - wx) * v00 + wx * v01)
            + wy * ((1.f - wx) * v10 + wx * v11);
    s[pi][k][ci] = v * om[pi][k][g];
  }
  __syncthreads();

  int t = threadIdx.x;
  int oi = (t & 127) * 2;
  int ph = (t >> 7) * 4;
  float acc0[4], acc1[4];
  #pragma unroll
  for (int q = 0; q < 4; ++q) { acc0[q] = bias[oi]; acc1[q] = bias[oi + 1]; }
  const float* w0 = w + (size_t)oi * C * 9;
  const float* w1 = w0 + C * 9;
  for (int ci = 0; ci < C; ci += 4) {
    float wr0[36], wr1[36];
    const float4* pw0 = (const float4*)(w0 + ci * 9);
    const float4* pw1 = (const float4*)(w1 + ci * 9);
    #pragma unroll
    for (int j = 0; j < 9; ++j) {
      float4 a = pw0[j]; float4 bq = pw1[j];
      wr0[4 * j] = a.x;  wr0[4 * j + 1] = a.y;  wr0[4 * j + 2] = a.z;  wr0[4 * j + 3] = a.w;
      wr1[4 * j] = bq.x; wr1[4 * j + 1] = bq.y; wr1[4 * j + 2] = bq.z; wr1[4 * j + 3] = bq.w;
    }
    #pragma unroll
    for (int k = 0; k < K; ++k) {
      #pragma unroll
      for (int q = 0; q < 4; ++q) {
        const float4 sv = *(const float4*)&s[ph + q][k][ci];
        acc0[q] += wr0[k] * sv.x + wr0[9 + k] * sv.y + wr0[18 + k] * sv.z + wr0[27 + k] * sv.w;
        acc1[q] += wr1[k] * sv.x + wr1[9 + k] * sv.y + wr1[18 + k] * sv.z + wr1[27 + k] * sv.w;
      }
    }
  }
  #pragma unroll
  for (int q = 0; q < 4; ++q) {
    out[((size_t)b * C + oi) * HW + p0 + ph + q]     = acc0[q];
    out[((size_t)b * C + oi + 1) * HW + p0 + ph + q] = acc1[q];
  }
}

extern "C" void kernel_launch(void* const* d_in, const int* in_sizes, int n_in,
                              void* d_out, int out_size, void* d_ws, size_t ws_size,
                              hipStream_t stream) {
  const float* x_main  = (const float*)d_in[0];
  const float* inpfeat = (const float*)d_in[1];
  const float* w1a = (const float*)d_in[2];
  const float* b1a = (const float*)d_in[3];
  const float* g1  = (const float*)d_in[4];
  const float* be1 = (const float*)d_in[5];
  const float* w1b = (const float*)d_in[6];
  const float* b1b = (const float*)d_in[7];
  const float* g2  = (const float*)d_in[8];
  const float* be2 = (const float*)d_in[9];
  const float* w1c = (const float*)d_in[10];
  const float* b1c = (const float*)d_in[11];
  const float* w2  = (const float*)d_in[12];
  const float* b2  = (const float*)d_in[13];
  const float* g3  = (const float*)d_in[14];
  const float* be3 = (const float*)d_in[15];
  const float* w_off = (const float*)d_in[16];
  const float* b_off = (const float*)d_in[17];
  const float* w_dcn = (const float*)d_in[18];
  const float* b_dcn = (const float*)d_in[19];

  float* warp_out = (float*)d_out;                      // output 0 [B,C,H,W]
  float* off_out  = warp_out + (size_t)B * C * HW;      // output 1 [B,C,H,W]

  // ---- workspace carve (bytes) ----
  char* ws = (char*)d_ws;
  float* r_inp = (float*)ws;                            //  2 MB  [B][CC][HW]
  float* fA    = (float*)(ws + (2u << 20));             // 16 MB  [B][C][HW] (also co)
  short* T     = (short*)(ws + (2u << 20) + (16u << 20));          // 9.44 MB bf16
  char*  wbase = ws + (2u << 20) + (16u << 20) + 9437184;
  short* wT1a  = (short*)(wbase);                       // 256*288
  short* wT1c  = (short*)(wbase + 147456 * 2);          // 256*256 (offset bytes: 294912)
  short* wT2   = (short*)(wbase + (147456 + 65536) * 2);
  short* wToff = (short*)(wbase + (147456 + 65536 + 589824) * 2);
  float* fB = warp_out;   // scratch until final deform write
  float* co = fA;

  // weight transforms (small, once per call)
  k_wt<1><<<dim3((256 * 288 + 255) / 256), 256, 0, stream>>>(w1a, wT1a, 256, 288);
  k_wt<1><<<dim3(256), 256, 0, stream>>>(w1c, wT1c, 256, 256);
  k_wt<9><<<dim3(256), 256, 0, stream>>>(w2, wT2, 256, 256);
  k_wt<9><<<dim3(216), 256, 0, stream>>>(w_off, wToff, 216, 256);

  k_resize<<<dim3((B * CC * HW) / 256), 256, 0, stream>>>(inpfeat, r_inp);
  // xcat = [r_inp(32ch) | x_main(256ch)] transposed to [HW][288] bf16
  k_transpose<<<dim3(HW / 64, 1, B), 256, 0, stream>>>(r_inp, T, CC, 288, 0);
  k_transpose<<<dim3(HW / 64, 8, B), 256, 0, stream>>>(x_main, T, C, 288, 32);
  k_mfma_conv<288, 256, 1><<<dim3(HW / 128, 4, B), 256, 0, stream>>>(T, wT1a, b1a, fA);
  k_gn_silu<<<dim3(GN, B), 256, 0, stream>>>(fA, fA, g1, be1);
  k_dw7<<<dim3(HW / 256, C, B), 256, 0, stream>>>(fA, w1b, b1b, fB);
  k_gn_silu<<<dim3(GN, B), 256, 0, stream>>>(fB, fB, g2, be2);
  k_transpose<<<dim3(HW / 64, 8, B), 256, 0, stream>>>(fB, T, C, 256, 0);
  k_mfma_conv<256, 256, 1><<<dim3(HW / 128, 4, B), 256, 0, stream>>>(T, wT1c, b1c, fA);
  k_transpose<<<dim3(HW / 64, 8, B), 256, 0, stream>>>(fA, T, C, 256, 0);
  k_mfma_conv<256, 256, 9><<<dim3(HW / 128, 4, B), 256, 0, stream>>>(T, wT2, b2, fB);
  k_gn_silu<<<dim3(GN, B), 256, 0, stream>>>(fB, off_out, g3, be3);
  k_transpose<<<dim3(HW / 64, 8, B), 256, 0, stream>>>(off_out, T, C, 256, 0);
  k_mfma_conv<256, 216, 9><<<dim3(HW / 128, 4, B), 256, 0, stream>>>(T, wToff, b_off, co);
  k_deform<<<dim3(HW / 8, B), 256, 0, stream>>>(x_main, co, w_dcn, b_dcn, warp_out);
}

// Round 3
// 657.359 us; speedup vs baseline: 9.3358x; 2.7659x over previous
//
#include <hip/hip_runtime.h>
#include <math.h>

constexpr int B = 4, C = 256, CC = 32, H = 64, W = 64, HW = H * W;
constexpr int G = 8, K = 9, GN = 32, CPG = C / GN;   // CPG = 8
constexpr int OFFC = 3 * G * K;                       // 216

typedef __attribute__((ext_vector_type(8))) short short8;
typedef __attribute__((ext_vector_type(4))) float f32x4;

__device__ inline short f2bf(float f) {
  unsigned u = __builtin_bit_cast(unsigned, f);
  return (short)((u + 0x7FFFu + ((u >> 16) & 1u)) >> 16);
}
__device__ inline float bf2f(short s) {
  unsigned u = ((unsigned)(unsigned short)s) << 16;
  return __builtin_bit_cast(float, u);
}

// ---------------- resize (2x2 avg pool: rate=2, align_corners=False) ---------
__global__ void k_resize(const float* __restrict__ in, float* __restrict__ out) {
  int idx = blockIdx.x * 256 + threadIdx.x;
  if (idx >= B * CC * HW) return;
  int p = idx & (HW - 1);
  int c = (idx / HW) % CC;
  int b = idx / (HW * CC);
  int y = p >> 6, x = p & 63;
  const float* src = in + ((size_t)b * CC + c) * (2 * H) * (2 * W);
  const float* r0 = src + (2 * y) * (2 * W) + 2 * x;
  const float* r1 = r0 + 2 * W;
  out[idx] = 0.25f * (r0[0] + r0[1] + r1[0] + r1[1]);
}

// ---------------- transpose+convert: fp32 [Csrc][HW] -> bf16 [HW][Cdst] ------
__global__ void k_transpose(const float* __restrict__ src, short* __restrict__ dst,
                            int Csrc, int Cdst, int coff) {
  int t = threadIdx.x;
  int p0 = blockIdx.x * 64;
  int cc0 = blockIdx.y * 32;
  int b = blockIdx.z;
  int px = t >> 2, cq = t & 3;
  const float* s = src + ((size_t)b * Csrc + cc0 + cq * 8) * HW + p0 + px;
  short8 v;
  #pragma unroll
  for (int j = 0; j < 8; ++j) v[j] = f2bf(s[(size_t)j * HW]);
  *(short8*)(dst + ((size_t)b * HW + p0 + px) * Cdst + coff + cc0 + cq * 8) = v;
}

// ---------------- weight transform: [Cout][Cin][T] fp32 -> [T][Cout][Cin] bf16
template<int TAPS>
__global__ void k_wt(const float* __restrict__ w, short* __restrict__ wT,
                     int Cout, int Cin) {
  int id = blockIdx.x * 256 + threadIdx.x;
  if (id >= Cout * Cin) return;
  if (TAPS == 1) {
    wT[id] = f2bf(w[id]);
  } else {
    int o = id / Cin, ci = id % Cin;
    #pragma unroll
    for (int k = 0; k < 9; ++k)
      wT[((size_t)k * Cout + o) * Cin + ci] = f2bf(w[(size_t)id * 9 + k]);
  }
}

// ---------------- MFMA implicit-GEMM conv (taps=1 or 9, pad=(taps==9)) -------
template<int CIN, int COUT, int TAPS>
__global__ __launch_bounds__(256) void k_mfma_conv(
    const short* __restrict__ gT, const short* __restrict__ wT,
    const float* __restrict__ bias, float* __restrict__ out) {
  constexpr int POS = (TAPS == 9) ? 4 * 66 : 128;   // staged positions
  constexpr int PSTR = 40;                          // u16 per position (80 B)
  __shared__ short lds[POS * PSTR];
  const int tid = threadIdx.x;
  const int lane = tid & 63, wv = tid >> 6;
  const int l15 = lane & 15, l4 = lane >> 4;
  const int b = blockIdx.z;
  const int o0 = blockIdx.y * 64;
  const int p0 = blockIdx.x * 128;
  const int y0 = p0 >> 6;                           // 2 image rows per block

  f32x4 acc[4][2];
  #pragma unroll
  for (int mt = 0; mt < 4; ++mt)
    #pragma unroll
    for (int nt = 0; nt < 2; ++nt) acc[mt][nt] = (f32x4)0.f;

  const short* gTb = gT + (size_t)b * HW * CIN;

  for (int ck = 0; ck < CIN / 32; ++ck) {
    const int ci0 = ck * 32;
    __syncthreads();
    for (int i = tid; i < POS * 4; i += 256) {
      int pos = i >> 2, cq = i & 3;
      short8 v = {0, 0, 0, 0, 0, 0, 0, 0};
      if (TAPS == 9) {
        int r = pos / 66;
        int cx = pos - r * 66 - 1;
        int y = y0 - 1 + r;
        if ((unsigned)y < (unsigned)H && (unsigned)cx < (unsigned)W)
          v = *(const short8*)(gTb + (size_t)(y * W + cx) * CIN + ci0 + cq * 8);
      } else {
        v = *(const short8*)(gTb + (size_t)(p0 + pos) * CIN + ci0 + cq * 8);
      }
      *(short8*)(lds + pos * PSTR + cq * 8) = v;
    }
    __syncthreads();

    for (int tap = 0; tap < TAPS; ++tap) {
      short8 a[4];
      #pragma unroll
      for (int mt = 0; mt < 4; ++mt) {
        int o_r = o0 + mt * 16 + l15;
        if (COUT % 64 == 0 || o_r < COUT)
          a[mt] = *(const short8*)(wT + ((size_t)tap * COUT + o_r) * CIN + ci0 + l4 * 8);
        else
          a[mt] = (short8){0, 0, 0, 0, 0, 0, 0, 0};
      }
      short8 bb[2];
      #pragma unroll
      for (int nt = 0; nt < 2; ++nt) {
        int pos;
        if (TAPS == 9) {
          int dy = tap / 3 - 1, dx = tap % 3 - 1;
          int row = (wv >> 1) + dy + 1;
          int col = (wv & 1) * 32 + nt * 16 + l15 + dx + 1;
          pos = row * 66 + col;
        } else {
          pos = wv * 32 + nt * 16 + l15;
        }
        bb[nt] = *(const short8*)(lds + pos * PSTR + l4 * 8);
      }
      #pragma unroll
      for (int mt = 0; mt < 4; ++mt)
        #pragma unroll
        for (int nt = 0; nt < 2; ++nt)
          acc[mt][nt] = __builtin_amdgcn_mfma_f32_16x16x32_bf16(
              a[mt], bb[nt], acc[mt][nt], 0, 0, 0);
    }
  }

  #pragma unroll
  for (int mt = 0; mt < 4; ++mt) {
    #pragma unroll
    for (int nt = 0; nt < 2; ++nt) {
      int p = p0 + wv * 32 + nt * 16 + l15;
      #pragma unroll
      for (int r = 0; r < 4; ++r) {
        int oo = o0 + mt * 16 + l4 * 4 + r;
        if (COUT % 64 == 0 || oo < COUT)
          out[((size_t)b * COUT + oo) * HW + p] = acc[mt][nt][r] + bias[oo];
      }
    }
  }
}

// ---------------- GroupNorm (32 groups) + SiLU, block per (group,b) ----------
__global__ void k_gn_silu(const float* __restrict__ in, float* __restrict__ out,
                          const float* __restrict__ gamma, const float* __restrict__ beta) {
  int g = blockIdx.x, b = blockIdx.y;
  const float* base = in + ((size_t)b * C + g * CPG) * HW;
  float s = 0.f, s2 = 0.f;
  for (int i = threadIdx.x; i < CPG * HW; i += 256) {
    float v = base[i]; s += v; s2 += v * v;
  }
  #pragma unroll
  for (int off = 32; off > 0; off >>= 1) {
    s  += __shfl_down(s, off);
    s2 += __shfl_down(s2, off);
  }
  __shared__ float sh[8];
  __shared__ float mi[2];
  int wid = threadIdx.x >> 6, lane = threadIdx.x & 63;
  if (lane == 0) { sh[wid] = s; sh[4 + wid] = s2; }
  __syncthreads();
  if (threadIdx.x == 0) {
    float ts = sh[0] + sh[1] + sh[2] + sh[3];
    float t2 = sh[4] + sh[5] + sh[6] + sh[7];
    float mean = ts * (1.f / (CPG * HW));
    float var  = t2 * (1.f / (CPG * HW)) - mean * mean;
    mi[0] = mean; mi[1] = rsqrtf(var + 1e-6f);
  }
  __syncthreads();
  float mean = mi[0], inv = mi[1];
  float* ob = out + ((size_t)b * C + g * CPG) * HW;
  for (int i = threadIdx.x; i < CPG * HW; i += 256) {
    int c = g * CPG + (i >> 12);
    float v = (base[i] - mean) * inv * gamma[c] + beta[c];
    ob[i] = v / (1.f + expf(-v));
  }
}

// ---------------- depthwise 7x7, pad 3 ---------------------------------------
__global__ void k_dw7(const float* __restrict__ in, const float* __restrict__ w,
                      const float* __restrict__ bias, float* __restrict__ out) {
  int p = blockIdx.x * 256 + threadIdx.x;
  int c = blockIdx.y, b = blockIdx.z;
  int y = p >> 6, x = p & 63;
  const float* src = in + ((size_t)b * C + c) * HW;
  const float* wk = w + c * 49;
  float acc = bias[c];
  for (int ky = 0; ky < 7; ++ky) {
    int yy = y + ky - 3;
    if ((unsigned)yy >= (unsigned)H) continue;
    const float* row = src + yy * W;
    #pragma unroll
    for (int kx = 0; kx < 7; ++kx) {
      int xx = x + kx - 3;
      if ((unsigned)xx >= (unsigned)W) continue;
      acc += wk[ky * 7 + kx] * row[xx];
    }
  }
  out[((size_t)b * C + c) * HW + p] = acc;
}

// ---------------- modulated deformable conv 3x3 via MFMA ---------------------
// xmT: [B][HW][C] bf16; co: [B][216][HW] fp32; wT: [9][256][256] bf16
// K-block of 32 channels == one deformable group -> uniform (dy,dx,m) per (p,k).
__global__ __launch_bounds__(256) void k_deform_mfma(
    const short* __restrict__ xmT, const float* __restrict__ co,
    const short* __restrict__ wT, const float* __restrict__ bias,
    float* __restrict__ out) {
  constexpr int PSTR = 40;                  // u16 per pixel slot (80 B)
  __shared__ short lds[128 * PSTR];         // 10 KB staged samples
  const int tid = threadIdx.x;
  const int lane = tid & 63, wv = tid >> 6;
  const int l15 = lane & 15, l4 = lane >> 4;
  const int b = blockIdx.z;
  const int o0 = blockIdx.y * 64;
  const int p0 = blockIdx.x * 128;

  f32x4 acc[4][2];
  #pragma unroll
  for (int mt = 0; mt < 4; ++mt)
    #pragma unroll
    for (int nt = 0; nt < 2; ++nt) acc[mt][nt] = (f32x4)0.f;

  const short* xb = xmT + (size_t)b * HW * C;
  const float* cob = co + (size_t)b * OFFC * HW;

  for (int g = 0; g < G; ++g) {
    for (int k = 0; k < K; ++k) {
      const int kh = k / 3 - 1, kw = k % 3 - 1;
      const float* dyp = cob + (size_t)((g * K + k) * 2) * HW + p0;
      const float* dxp = dyp + HW;
      const float* mlp = cob + (size_t)(144 + g * K + k) * HW + p0;
      __syncthreads();
      // stage modulated bilinear samples: s[pl][c], c in [g*32, g*32+32)
      #pragma unroll
      for (int it = 0; it < 2; ++it) {
        int i = tid + it * 256;
        int pl = i >> 2, cq = i & 3;
        float dy = dyp[pl], dx = dxp[pl];
        float m = 1.f / (1.f + expf(-mlp[pl]));
        int py = (p0 + pl) >> 6, px = (p0 + pl) & 63;
        float yy = (float)(py + kh) + dy;
        float xx = (float)(px + kw) + dx;
        float yf = floorf(yy), xf = floorf(xx);
        float wy = yy - yf, wx = xx - xf;
        int y0 = (int)yf, x0 = (int)xf;
        bool yv0 = (unsigned)y0 < (unsigned)H, yv1 = (unsigned)(y0 + 1) < (unsigned)H;
        bool xv0 = (unsigned)x0 < (unsigned)W, xv1 = (unsigned)(x0 + 1) < (unsigned)W;
        const short8 z = {0, 0, 0, 0, 0, 0, 0, 0};
        const short* base = xb + g * 32 + cq * 8;
        short8 v00 = (yv0 && xv0) ? *(const short8*)(base + (size_t)(y0 * W + x0) * C) : z;
        short8 v01 = (yv0 && xv1) ? *(const short8*)(base + (size_t)(y0 * W + x0 + 1) * C) : z;
        short8 v10 = (yv1 && xv0) ? *(const short8*)(base + (size_t)((y0 + 1) * W + x0) * C) : z;
        short8 v11 = (yv1 && xv1) ? *(const short8*)(base + (size_t)((y0 + 1) * W + x0 + 1) * C) : z;
        float w00 = (1.f - wy) * (1.f - wx) * m, w01 = (1.f - wy) * wx * m;
        float w10 = wy * (1.f - wx) * m,         w11 = wy * wx * m;
        short8 r;
        #pragma unroll
        for (int j = 0; j < 8; ++j)
          r[j] = f2bf(w00 * bf2f(v00[j]) + w01 * bf2f(v01[j]) +
                      w10 * bf2f(v10[j]) + w11 * bf2f(v11[j]));
        *(short8*)(lds + pl * PSTR + cq * 8) = r;
      }
      __syncthreads();
      // MFMA: A = w_dcn[tap=k][o][g*32..], B = staged samples
      short8 a[4];
      #pragma unroll
      for (int mt = 0; mt < 4; ++mt)
        a[mt] = *(const short8*)(wT + ((size_t)k * C + o0 + mt * 16 + l15) * C + g * 32 + l4 * 8);
      short8 bb[2];
      #pragma unroll
      for (int nt = 0; nt < 2; ++nt)
        bb[nt] = *(const short8*)(lds + (wv * 32 + nt * 16 + l15) * PSTR + l4 * 8);
      #pragma unroll
      for (int mt = 0; mt < 4; ++mt)
        #pragma unroll
        for (int nt = 0; nt < 2; ++nt)
          acc[mt][nt] = __builtin_amdgcn_mfma_f32_16x16x32_bf16(
              a[mt], bb[nt], acc[mt][nt], 0, 0, 0);
    }
  }

  #pragma unroll
  for (int mt = 0; mt < 4; ++mt) {
    #pragma unroll
    for (int nt = 0; nt < 2; ++nt) {
      int p = p0 + wv * 32 + nt * 16 + l15;
      #pragma unroll
      for (int r = 0; r < 4; ++r) {
        int oo = o0 + mt * 16 + l4 * 4 + r;
        out[((size_t)b * C + oo) * HW + p] = acc[mt][nt][r] + bias[oo];
      }
    }
  }
}

extern "C" void kernel_launch(void* const* d_in, const int* in_sizes, int n_in,
                              void* d_out, int out_size, void* d_ws, size_t ws_size,
                              hipStream_t stream) {
  const float* x_main  = (const float*)d_in[0];
  const float* inpfeat = (const float*)d_in[1];
  const float* w1a = (const float*)d_in[2];
  const float* b1a = (const float*)d_in[3];
  const float* g1  = (const float*)d_in[4];
  const float* be1 = (const float*)d_in[5];
  const float* w1b = (const float*)d_in[6];
  const float* b1b = (const float*)d_in[7];
  const float* g2  = (const float*)d_in[8];
  const float* be2 = (const float*)d_in[9];
  const float* w1c = (const float*)d_in[10];
  const float* b1c = (const float*)d_in[11];
  const float* w2  = (const float*)d_in[12];
  const float* b2  = (const float*)d_in[13];
  const float* g3  = (const float*)d_in[14];
  const float* be3 = (const float*)d_in[15];
  const float* w_off = (const float*)d_in[16];
  const float* b_off = (const float*)d_in[17];
  const float* w_dcn = (const float*)d_in[18];
  const float* b_dcn = (const float*)d_in[19];

  float* warp_out = (float*)d_out;                      // output 0 [B,C,H,W]
  float* off_out  = warp_out + (size_t)B * C * HW;      // output 1 [B,C,H,W]

  // ---- workspace carve (bytes) ----
  char* ws = (char*)d_ws;
  float* r_inp = (float*)ws;                            //  2 MB [B][CC][HW]; later wTd
  float* fA    = (float*)(ws + (2u << 20));             // 16 MB [B][C][HW] (also co)
  short* T     = (short*)(ws + (2u << 20) + (16u << 20));   // 9.44 MB bf16 (also xmT)
  char*  wbase = ws + (2u << 20) + (16u << 20) + 9437184;
  short* wT1a  = (short*)(wbase);                       // 256*288
  short* wT1c  = (short*)(wbase + 294912);              // 256*256
  short* wT2   = (short*)(wbase + 294912 + 131072);     // 9*256*256
  short* wToff = (short*)(wbase + 294912 + 131072 + 1179648);  // 9*216*256
  short* wTd   = (short*)r_inp;                         // 9*256*256 (after r_inp dead)
  float* fB = warp_out;   // scratch until final deform write
  float* co = fA;

  k_wt<1><<<dim3((256 * 288 + 255) / 256), 256, 0, stream>>>(w1a, wT1a, 256, 288);
  k_wt<1><<<dim3(256), 256, 0, stream>>>(w1c, wT1c, 256, 256);
  k_wt<9><<<dim3(256), 256, 0, stream>>>(w2, wT2, 256, 256);
  k_wt<9><<<dim3(216), 256, 0, stream>>>(w_off, wToff, 216, 256);

  k_resize<<<dim3((B * CC * HW) / 256), 256, 0, stream>>>(inpfeat, r_inp);
  k_transpose<<<dim3(HW / 64, 1, B), 256, 0, stream>>>(r_inp, T, CC, 288, 0);
  k_transpose<<<dim3(HW / 64, 8, B), 256, 0, stream>>>(x_main, T, C, 288, 32);
  k_mfma_conv<288, 256, 1><<<dim3(HW / 128, 4, B), 256, 0, stream>>>(T, wT1a, b1a, fA);
  k_wt<9><<<dim3(256), 256, 0, stream>>>(w_dcn, wTd, 256, 256);   // r_inp now dead
  k_gn_silu<<<dim3(GN, B), 256, 0, stream>>>(fA, fA, g1, be1);
  k_dw7<<<dim3(HW / 256, C, B), 256, 0, stream>>>(fA, w1b, b1b, fB);
  k_gn_silu<<<dim3(GN, B), 256, 0, stream>>>(fB, fB, g2, be2);
  k_transpose<<<dim3(HW / 64, 8, B), 256, 0, stream>>>(fB, T, C, 256, 0);
  k_mfma_conv<256, 256, 1><<<dim3(HW / 128, 4, B), 256, 0, stream>>>(T, wT1c, b1c, fA);
  k_transpose<<<dim3(HW / 64, 8, B), 256, 0, stream>>>(fA, T, C, 256, 0);
  k_mfma_conv<256, 256, 9><<<dim3(HW / 128, 4, B), 256, 0, stream>>>(T, wT2, b2, fB);
  k_gn_silu<<<dim3(GN, B), 256, 0, stream>>>(fB, off_out, g3, be3);
  k_transpose<<<dim3(HW / 64, 8, B), 256, 0, stream>>>(off_out, T, C, 256, 0);
  k_mfma_conv<256, 216, 9><<<dim3(HW / 128, 4, B), 256, 0, stream>>>(T, wToff, b_off, co);
  // T dead -> reuse as xmT [B][HW][256] bf16 (8 MB <= 9.44 MB)
  k_transpose<<<dim3(HW / 64, 8, B), 256, 0, stream>>>(x_main, T, C, 256, 0);
  k_deform_mfma<<<dim3(HW / 128, 4, B), 256, 0, stream>>>(T, co, wTd, b_dcn, warp_out);
}

// Round 4
// 538.295 us; speedup vs baseline: 11.4008x; 1.2212x over previous
//
#include <hip/hip_runtime.h>
#include <math.h>

constexpr int B = 4, C = 256, CC = 32, H = 64, W = 64, HW = H * W;
constexpr int G = 8, K = 9, GN = 32, CPG = C / GN;   // CPG = 8
constexpr int OFFC = 3 * G * K;                       // 216

typedef __attribute__((ext_vector_type(8))) short short8;
typedef __attribute__((ext_vector_type(4))) float f32x4;

__device__ inline short f2bf(float f) {
  unsigned u = __builtin_bit_cast(unsigned, f);
  return (short)((u + 0x7FFFu + ((u >> 16) & 1u)) >> 16);
}
__device__ inline float bf2f(short s) {
  unsigned u = ((unsigned)(unsigned short)s) << 16;
  return __builtin_bit_cast(float, u);
}

// ---------------- resize (2x2 avg pool: rate=2, align_corners=False) ---------
__global__ void k_resize(const float* __restrict__ in, float* __restrict__ out) {
  int idx = blockIdx.x * 256 + threadIdx.x;
  if (idx >= B * CC * HW) return;
  int p = idx & (HW - 1);
  int c = (idx / HW) % CC;
  int b = idx / (HW * CC);
  int y = p >> 6, x = p & 63;
  const float* src = in + ((size_t)b * CC + c) * (2 * H) * (2 * W);
  const float* r0 = src + (2 * y) * (2 * W) + 2 * x;
  const float* r1 = r0 + 2 * W;
  out[idx] = 0.25f * (r0[0] + r0[1] + r1[0] + r1[1]);
}

// ---------------- transpose+convert: fp32 [Csrc][HW] -> bf16 [HW][Cdst] ------
__global__ void k_transpose(const float* __restrict__ src, short* __restrict__ dst,
                            int Csrc, int Cdst, int coff) {
  int t = threadIdx.x;
  int p0 = blockIdx.x * 64;
  int cc0 = blockIdx.y * 32;
  int b = blockIdx.z;
  int px = t >> 2, cq = t & 3;
  const float* s = src + ((size_t)b * Csrc + cc0 + cq * 8) * HW + p0 + px;
  short8 v;
  #pragma unroll
  for (int j = 0; j < 8; ++j) v[j] = f2bf(s[(size_t)j * HW]);
  *(short8*)(dst + ((size_t)b * HW + p0 + px) * Cdst + coff + cc0 + cq * 8) = v;
}

// ---------------- weight transform: [Cout][Cin][T] fp32 -> [T][Cout][Cin] bf16
template<int TAPS>
__global__ void k_wt(const float* __restrict__ w, short* __restrict__ wT,
                     int Cout, int Cin) {
  int id = blockIdx.x * 256 + threadIdx.x;
  if (id >= Cout * Cin) return;
  if (TAPS == 1) {
    wT[id] = f2bf(w[id]);
  } else {
    int o = id / Cin, ci = id % Cin;
    #pragma unroll
    for (int k = 0; k < 9; ++k)
      wT[((size_t)k * Cout + o) * Cin + ci] = f2bf(w[(size_t)id * 9 + k]);
  }
}

// ---------------- MFMA implicit-GEMM conv (taps=1 or 9, pad=(taps==9)) -------
template<int CIN, int COUT, int TAPS>
__global__ __launch_bounds__(256) void k_mfma_conv(
    const short* __restrict__ gT, const short* __restrict__ wT,
    const float* __restrict__ bias, float* __restrict__ out) {
  constexpr int POS = (TAPS == 9) ? 4 * 66 : 128;   // staged positions
  constexpr int PSTR = 40;                          // u16 per position (80 B)
  __shared__ short lds[POS * PSTR];
  const int tid = threadIdx.x;
  const int lane = tid & 63, wv = tid >> 6;
  const int l15 = lane & 15, l4 = lane >> 4;
  const int b = blockIdx.z;
  const int o0 = blockIdx.y * 64;
  const int p0 = blockIdx.x * 128;
  const int y0 = p0 >> 6;                           // 2 image rows per block

  f32x4 acc[4][2];
  #pragma unroll
  for (int mt = 0; mt < 4; ++mt)
    #pragma unroll
    for (int nt = 0; nt < 2; ++nt) acc[mt][nt] = (f32x4)0.f;

  const short* gTb = gT + (size_t)b * HW * CIN;

  for (int ck = 0; ck < CIN / 32; ++ck) {
    const int ci0 = ck * 32;
    __syncthreads();
    for (int i = tid; i < POS * 4; i += 256) {
      int pos = i >> 2, cq = i & 3;
      short8 v = {0, 0, 0, 0, 0, 0, 0, 0};
      if (TAPS == 9) {
        int r = pos / 66;
        int cx = pos - r * 66 - 1;
        int y = y0 - 1 + r;
        if ((unsigned)y < (unsigned)H && (unsigned)cx < (unsigned)W)
          v = *(const short8*)(gTb + (size_t)(y * W + cx) * CIN + ci0 + cq * 8);
      } else {
        v = *(const short8*)(gTb + (size_t)(p0 + pos) * CIN + ci0 + cq * 8);
      }
      *(short8*)(lds + pos * PSTR + cq * 8) = v;
    }
    __syncthreads();

    for (int tap = 0; tap < TAPS; ++tap) {
      short8 a[4];
      #pragma unroll
      for (int mt = 0; mt < 4; ++mt) {
        int o_r = o0 + mt * 16 + l15;
        if (COUT % 64 == 0 || o_r < COUT)
          a[mt] = *(const short8*)(wT + ((size_t)tap * COUT + o_r) * CIN + ci0 + l4 * 8);
        else
          a[mt] = (short8){0, 0, 0, 0, 0, 0, 0, 0};
      }
      short8 bb[2];
      #pragma unroll
      for (int nt = 0; nt < 2; ++nt) {
        int pos;
        if (TAPS == 9) {
          int dy = tap / 3 - 1, dx = tap % 3 - 1;
          int row = (wv >> 1) + dy + 1;
          int col = (wv & 1) * 32 + nt * 16 + l15 + dx + 1;
          pos = row * 66 + col;
        } else {
          pos = wv * 32 + nt * 16 + l15;
        }
        bb[nt] = *(const short8*)(lds + pos * PSTR + l4 * 8);
      }
      #pragma unroll
      for (int mt = 0; mt < 4; ++mt)
        #pragma unroll
        for (int nt = 0; nt < 2; ++nt)
          acc[mt][nt] = __builtin_amdgcn_mfma_f32_16x16x32_bf16(
              a[mt], bb[nt], acc[mt][nt], 0, 0, 0);
    }
  }

  #pragma unroll
  for (int mt = 0; mt < 4; ++mt) {
    #pragma unroll
    for (int nt = 0; nt < 2; ++nt) {
      int p = p0 + wv * 32 + nt * 16 + l15;
      #pragma unroll
      for (int r = 0; r < 4; ++r) {
        int oo = o0 + mt * 16 + l4 * 4 + r;
        if (COUT % 64 == 0 || oo < COUT)
          out[((size_t)b * COUT + oo) * HW + p] = acc[mt][nt][r] + bias[oo];
      }
    }
  }
}

// ---------------- GroupNorm (32 groups) + SiLU, block per (group,b) ----------
__global__ void k_gn_silu(const float* __restrict__ in, float* __restrict__ out,
                          const float* __restrict__ gamma, const float* __restrict__ beta) {
  int g = blockIdx.x, b = blockIdx.y;
  const float* base = in + ((size_t)b * C + g * CPG) * HW;
  float s = 0.f, s2 = 0.f;
  for (int i = threadIdx.x; i < CPG * HW; i += 256) {
    float v = base[i]; s += v; s2 += v * v;
  }
  #pragma unroll
  for (int off = 32; off > 0; off >>= 1) {
    s  += __shfl_down(s, off);
    s2 += __shfl_down(s2, off);
  }
  __shared__ float sh[8];
  __shared__ float mi[2];
  int wid = threadIdx.x >> 6, lane = threadIdx.x & 63;
  if (lane == 0) { sh[wid] = s; sh[4 + wid] = s2; }
  __syncthreads();
  if (threadIdx.x == 0) {
    float ts = sh[0] + sh[1] + sh[2] + sh[3];
    float t2 = sh[4] + sh[5] + sh[6] + sh[7];
    float mean = ts * (1.f / (CPG * HW));
    float var  = t2 * (1.f / (CPG * HW)) - mean * mean;
    mi[0] = mean; mi[1] = rsqrtf(var + 1e-6f);
  }
  __syncthreads();
  float mean = mi[0], inv = mi[1];
  float* ob = out + ((size_t)b * C + g * CPG) * HW;
  for (int i = threadIdx.x; i < CPG * HW; i += 256) {
    int c = g * CPG + (i >> 12);
    float v = (base[i] - mean) * inv * gamma[c] + beta[c];
    ob[i] = v / (1.f + expf(-v));
  }
}

// ---------------- depthwise 7x7, pad 3 — 4 px per thread, float4 row loads ---
__global__ void k_dw7(const float* __restrict__ in, const float* __restrict__ w,
                      const float* __restrict__ bias, float* __restrict__ out) {
  int t = blockIdx.x * 256 + threadIdx.x;   // 0..1023 per (c,b)
  int c = blockIdx.y, b = blockIdx.z;
  int x4 = (t & 15) * 4;
  int y = t >> 4;
  const float* src = in + ((size_t)b * C + c) * HW;
  const float* wk = w + c * 49;
  float bz = bias[c];
  float a0 = bz, a1 = bz, a2 = bz, a3 = bz;
  const float4 z4 = make_float4(0.f, 0.f, 0.f, 0.f);
  #pragma unroll
  for (int ky = 0; ky < 7; ++ky) {
    int yy = y + ky - 3;
    if ((unsigned)yy >= (unsigned)H) continue;
    const float* row = src + yy * W;
    float4 A = (x4 >= 4)  ? *(const float4*)(row + x4 - 4) : z4;
    float4 Bm = *(const float4*)(row + x4);
    float4 Cx = (x4 <= 56) ? *(const float4*)(row + x4 + 4) : z4;
    float rb[12] = {A.x, A.y, A.z, A.w, Bm.x, Bm.y, Bm.z, Bm.w, Cx.x, Cx.y, Cx.z, Cx.w};
    #pragma unroll
    for (int kx = 0; kx < 7; ++kx) {
      float wv = wk[ky * 7 + kx];
      a0 += wv * rb[kx + 1];
      a1 += wv * rb[kx + 2];
      a2 += wv * rb[kx + 3];
      a3 += wv * rb[kx + 4];
    }
  }
  *(float4*)(out + ((size_t)b * C + c) * HW + y * W + x4) = make_float4(a0, a1, a2, a3);
}

// ---------------- modulated deformable conv 3x3 via MFMA (v3) ----------------
// 512 threads: 8 waves = 4 o-tiles x 2 px-halves; 64-px tile; all 256 outputs
// per block -> sampling done once. Per group g: A) per-(tap,px) weights/offsets
// (invalid corners = weight 0, clamped offset), B) branch-free modulated
// bilinear staging of s[9][64][32ch] bf16, C) 72 MFMAs/wave.
__global__ __launch_bounds__(512) void k_deform_mfma(
    const short* __restrict__ xmT, const float* __restrict__ co,
    const short* __restrict__ wT, const float* __restrict__ bias,
    float* __restrict__ out) {
  constexpr int PSTR = 40;                  // u16 per pixel slot (80 B)
  __shared__ short s[9 * 64 * PSTR];        // 46080 B
  __shared__ float4 wgt[9][64];             // 9216 B
  __shared__ int4   ofs[9][64];             // 9216 B
  const int tid = threadIdx.x;
  const int lane = tid & 63, wv = tid >> 6;
  const int l15 = lane & 15, l4 = lane >> 4;
  const int b = blockIdx.y;
  const int p0 = blockIdx.x * 64;
  const int o0 = (wv >> 1) * 64;            // wave's output-channel tile
  const int pt = wv & 1;                    // wave's pixel half (32 px)

  f32x4 acc[4][2];
  #pragma unroll
  for (int mt = 0; mt < 4; ++mt)
    #pragma unroll
    for (int nt = 0; nt < 2; ++nt) acc[mt][nt] = (f32x4)0.f;

  const short* xb = xmT + (size_t)b * HW * C;
  const float* cob = co + (size_t)b * OFFC * HW;

  for (int g = 0; g < G; ++g) {
    __syncthreads();
    // phase A: weights/offsets per (tap, pixel)
    for (int i = tid; i < K * 64; i += 512) {
      int k = i >> 6, pl = i & 63;
      int p = p0 + pl;
      float dy = cob[(size_t)((g * K + k) * 2) * HW + p];
      float dx = cob[(size_t)((g * K + k) * 2 + 1) * HW + p];
      float ml = cob[(size_t)(144 + g * K + k) * HW + p];
      float m = 1.f / (1.f + expf(-ml));
      int kh = k / 3 - 1, kw = k % 3 - 1;
      int py = p >> 6, px = p & 63;
      float yy = (float)(py + kh) + dy;
      float xx = (float)(px + kw) + dx;
      float yf = floorf(yy), xf = floorf(xx);
      float wy = yy - yf, wx = xx - xf;
      int y0 = (int)yf, x0 = (int)xf;
      bool yv0 = (unsigned)y0 < (unsigned)H, yv1 = (unsigned)(y0 + 1) < (unsigned)H;
      bool xv0 = (unsigned)x0 < (unsigned)W, xv1 = (unsigned)(x0 + 1) < (unsigned)W;
      int yc0 = min(max(y0, 0), H - 1), yc1 = min(max(y0 + 1, 0), H - 1);
      int xc0 = min(max(x0, 0), W - 1), xc1 = min(max(x0 + 1, 0), W - 1);
      float w00 = (yv0 && xv0) ? (1.f - wy) * (1.f - wx) * m : 0.f;
      float w01 = (yv0 && xv1) ? (1.f - wy) * wx * m : 0.f;
      float w10 = (yv1 && xv0) ? wy * (1.f - wx) * m : 0.f;
      float w11 = (yv1 && xv1) ? wy * wx * m : 0.f;
      wgt[k][pl] = make_float4(w00, w01, w10, w11);
      ofs[k][pl] = make_int4((yc0 * W + xc0) * C, (yc0 * W + xc1) * C,
                             (yc1 * W + xc0) * C, (yc1 * W + xc1) * C);
    }
    __syncthreads();
    // phase B: branch-free modulated bilinear staging
    for (int i = tid; i < K * 256; i += 512) {
      int k = i >> 8, r = i & 255, pl = r >> 2, cq = r & 3;
      float4 ww = wgt[k][pl];
      int4 o4 = ofs[k][pl];
      const short* base = xb + g * 32 + cq * 8;
      short8 v00 = *(const short8*)(base + o4.x);
      short8 v01 = *(const short8*)(base + o4.y);
      short8 v10 = *(const short8*)(base + o4.z);
      short8 v11 = *(const short8*)(base + o4.w);
      short8 rr;
      #pragma unroll
      for (int j = 0; j < 8; ++j)
        rr[j] = f2bf(ww.x * bf2f(v00[j]) + ww.y * bf2f(v01[j]) +
                     ww.z * bf2f(v10[j]) + ww.w * bf2f(v11[j]));
      *(short8*)(s + (k * 64 + pl) * PSTR + cq * 8) = rr;
    }
    __syncthreads();
    // phase C: MFMA over 9 taps
    for (int k = 0; k < K; ++k) {
      short8 a[4];
      #pragma unroll
      for (int mt = 0; mt < 4; ++mt)
        a[mt] = *(const short8*)(wT + ((size_t)k * C + o0 + mt * 16 + l15) * C + g * 32 + l4 * 8);
      short8 bb[2];
      #pragma unroll
      for (int nt = 0; nt < 2; ++nt)
        bb[nt] = *(const short8*)(s + (k * 64 + pt * 32 + nt * 16 + l15) * PSTR + l4 * 8);
      #pragma unroll
      for (int mt = 0; mt < 4; ++mt)
        #pragma unroll
        for (int nt = 0; nt < 2; ++nt)
          acc[mt][nt] = __builtin_amdgcn_mfma_f32_16x16x32_bf16(
              a[mt], bb[nt], acc[mt][nt], 0, 0, 0);
    }
  }

  #pragma unroll
  for (int mt = 0; mt < 4; ++mt) {
    #pragma unroll
    for (int nt = 0; nt < 2; ++nt) {
      int p = p0 + pt * 32 + nt * 16 + l15;
      #pragma unroll
      for (int r = 0; r < 4; ++r) {
        int oo = o0 + mt * 16 + l4 * 4 + r;
        out[((size_t)b * C + oo) * HW + p] = acc[mt][nt][r] + bias[oo];
      }
    }
  }
}

extern "C" void kernel_launch(void* const* d_in, const int* in_sizes, int n_in,
                              void* d_out, int out_size, void* d_ws, size_t ws_size,
                              hipStream_t stream) {
  const float* x_main  = (const float*)d_in[0];
  const float* inpfeat = (const float*)d_in[1];
  const float* w1a = (const float*)d_in[2];
  const float* b1a = (const float*)d_in[3];
  const float* g1  = (const float*)d_in[4];
  const float* be1 = (const float*)d_in[5];
  const float* w1b = (const float*)d_in[6];
  const float* b1b = (const float*)d_in[7];
  const float* g2  = (const float*)d_in[8];
  const float* be2 = (const float*)d_in[9];
  const float* w1c = (const float*)d_in[10];
  const float* b1c = (const float*)d_in[11];
  const float* w2  = (const float*)d_in[12];
  const float* b2  = (const float*)d_in[13];
  const float* g3  = (const float*)d_in[14];
  const float* be3 = (const float*)d_in[15];
  const float* w_off = (const float*)d_in[16];
  const float* b_off = (const float*)d_in[17];
  const float* w_dcn = (const float*)d_in[18];
  const float* b_dcn = (const float*)d_in[19];

  float* warp_out = (float*)d_out;                      // output 0 [B,C,H,W]
  float* off_out  = warp_out + (size_t)B * C * HW;      // output 1 [B,C,H,W]

  // ---- workspace carve (bytes) ----
  char* ws = (char*)d_ws;
  float* r_inp = (float*)ws;                            //  2 MB [B][CC][HW]; later wTd
  float* fA    = (float*)(ws + (2u << 20));             // 16 MB [B][C][HW] (also co)
  short* T     = (short*)(ws + (2u << 20) + (16u << 20));   // 9.44 MB bf16 (also xmT)
  char*  wbase = ws + (2u << 20) + (16u << 20) + 9437184;
  short* wT1a  = (short*)(wbase);                       // 256*288
  short* wT1c  = (short*)(wbase + 294912);              // 256*256
  short* wT2   = (short*)(wbase + 294912 + 131072);     // 9*256*256
  short* wToff = (short*)(wbase + 294912 + 131072 + 1179648);  // 9*216*256
  short* wTd   = (short*)r_inp;                         // 9*256*256 (after r_inp dead)
  float* fB = warp_out;   // scratch until final deform write
  float* co = fA;

  k_wt<1><<<dim3((256 * 288 + 255) / 256), 256, 0, stream>>>(w1a, wT1a, 256, 288);
  k_wt<1><<<dim3(256), 256, 0, stream>>>(w1c, wT1c, 256, 256);
  k_wt<9><<<dim3(256), 256, 0, stream>>>(w2, wT2, 256, 256);
  k_wt<9><<<dim3(216), 256, 0, stream>>>(w_off, wToff, 216, 256);

  k_resize<<<dim3((B * CC * HW) / 256), 256, 0, stream>>>(inpfeat, r_inp);
  k_transpose<<<dim3(HW / 64, 1, B), 256, 0, stream>>>(r_inp, T, CC, 288, 0);
  k_transpose<<<dim3(HW / 64, 8, B), 256, 0, stream>>>(x_main, T, C, 288, 32);
  k_mfma_conv<288, 256, 1><<<dim3(HW / 128, 4, B), 256, 0, stream>>>(T, wT1a, b1a, fA);
  k_wt<9><<<dim3(256), 256, 0, stream>>>(w_dcn, wTd, 256, 256);   // r_inp now dead
  k_gn_silu<<<dim3(GN, B), 256, 0, stream>>>(fA, fA, g1, be1);
  k_dw7<<<dim3(HW / 1024, C, B), 256, 0, stream>>>(fA, w1b, b1b, fB);
  k_gn_silu<<<dim3(GN, B), 256, 0, stream>>>(fB, fB, g2, be2);
  k_transpose<<<dim3(HW / 64, 8, B), 256, 0, stream>>>(fB, T, C, 256, 0);
  k_mfma_conv<256, 256, 1><<<dim3(HW / 128, 4, B), 256, 0, stream>>>(T, wT1c, b1c, fA);
  k_transpose<<<dim3(HW / 64, 8, B), 256, 0, stream>>>(fA, T, C, 256, 0);
  k_mfma_conv<256, 256, 9><<<dim3(HW / 128, 4, B), 256, 0, stream>>>(T, wT2, b2, fB);
  k_gn_silu<<<dim3(GN, B), 256, 0, stream>>>(fB, off_out, g3, be3);
  k_transpose<<<dim3(HW / 64, 8, B), 256, 0, stream>>>(off_out, T, C, 256, 0);
  k_mfma_conv<256, 216, 9><<<dim3(HW / 128, 4, B), 256, 0, stream>>>(T, wToff, b_off, co);
  // T dead -> reuse as xmT [B][HW][256] bf16 (8 MB <= 9.44 MB)
  k_transpose<<<dim3(HW / 64, 8, B), 256, 0, stream>>>(x_main, T, C, 256, 0);
  k_deform_mfma<<<dim3(HW / 64, B), 512, 0, stream>>>(T, co, wTd, b_dcn, warp_out);
}